// Round 4
// baseline (1535.988 us; speedup 1.0000x reference)
//
#include <hip/hip_runtime.h>
#include <hip/hip_bf16.h>

typedef __attribute__((ext_vector_type(8))) short short8;
typedef __attribute__((ext_vector_type(4))) short short4v;
typedef __attribute__((ext_vector_type(4))) float f32x4;
typedef __attribute__((ext_vector_type(4))) int   int4v;
typedef __attribute__((ext_vector_type(2))) int   int2v;

#define NFEAT 64
#define IN_DIM 192
#define HID 128
#define OUTD 64
#define WTILE 16
#define GRID 512
#define TPB 512
#define NWAVES (GRID*8)     // 4096 independent wave streams
#define W1STR 200           // shorts per W1 row (192 + 8 pad; 2-way on b128, free)
#define W2FSTR 40           // shorts per W2 fragment row (32 + 8 pad; 2-way, free)

#define W1_SH  (HID*W1STR)        // 25600 shorts = 51200 B
#define W2F_SH (16*16*W2FSTR)     // 10240 shorts = 20480 B
#define SMEM_BYTES (W1_SH*2 + W2F_SH*2 + HID*4 + OUTD*4 + OUTD*4)  // 72704 B -> 2 blocks/CU

#define LOG2E 1.4426950408889634f
#define LN2   0.6931471805599453f

__device__ __forceinline__ short f2bf(float f) {
  __hip_bfloat16 b = __float2bfloat16(f);   // RNE; pairs fuse to v_cvt_pk_bf16_f32
  short s; __builtin_memcpy(&s, &b, 2); return s;
}
__device__ __forceinline__ float bf2f(short b) {
  unsigned int u = ((unsigned int)(unsigned short)b) << 16;
  float f; __builtin_memcpy(&f, &u, 4); return f;
}
// H'' = log2(1 + 2^z)   (softplus with ln2 folded into W1/W2/b2)
__device__ __forceinline__ float h2(float z) {
  return __builtin_log2f(1.0f + __builtin_exp2f(z));
}

// edges arrive as int64 (x64 on) or int32. int64 => odd int32 words all zero.
__global__ void detect_mode(const int* __restrict__ edges_i, int* __restrict__ flag) {
  __shared__ int cnt;
  if (threadIdx.x == 0) cnt = 0;
  __syncthreads();
  if (edges_i[2 * threadIdx.x + 1] == 0) atomicAdd(&cnt, 1);
  __syncthreads();
  if (threadIdx.x == 0) flag[0] = (cnt >= 250) ? 1 : 0;
}

__global__ __launch_bounds__(TPB, 4) void edge_mlp(
    const float* __restrict__ edge_state,
    const int*   __restrict__ edges_i,
    const float* __restrict__ node_state,
    const float* __restrict__ W1g, const float* __restrict__ b1g,
    const float* __restrict__ W2g, const float* __restrict__ b2g,
    float* __restrict__ out, const int* __restrict__ flag, int tiles16)
{
  extern __shared__ char smem[];
  unsigned short* W1l  = (unsigned short*)smem;
  unsigned short* W2fl = W1l + W1_SH;
  float* b1l = (float*)(W2fl + W2F_SH);
  float* b2l = b1l + HID;
  float* b2s = b2l + OUTD;

  const int tid  = threadIdx.x;
  const int w    = tid >> 6;          // wave 0..7 (fully independent after staging)
  const int lane = tid & 63;
  const int lg   = (lane >> 4) & 3;   // lane-group = MFMA k-slice selector
  const int li   = lane & 15;         // lane-in-group = edge (B) / row (A)

  const bool idx64 = (flag[0] != 0);

  // ---- stage weights (constants folded in) ----
  if (tid < OUTD) b2s[tid] = 0.f;
  __syncthreads();
  #pragma unroll 1
  for (int g = tid; g < (HID*IN_DIM/4); g += TPB) {      // W1' = W1 * log2e
    int row = g / 48, c4 = g - row*48;
    f32x4 v = *(const f32x4*)(W1g + row*IN_DIM + c4*4);
    short4v s = { f2bf(v[0]*LOG2E), f2bf(v[1]*LOG2E), f2bf(v[2]*LOG2E), f2bf(v[3]*LOG2E) };
    *(short4v*)(W1l + row*W1STR + c4*4) = s;
  }
  #pragma unroll 1
  for (int g = tid; g < (OUTD*HID/4); g += TPB) {        // W2' = W2 * ln2, fragment-ordered
    int f = g >> 5, c4 = g & 31;
    f32x4 v = *(const f32x4*)(W2g + f*HID + c4*4);
    int ni = f >> 4, liw = f & 15;
    float psum = 0.f;
    #pragma unroll
    for (int e = 0; e < 4; ++e) {
      short b = f2bf(v[e]*LN2);
      psum += bf2f(b);
      int h = c4*4 + e;
      int q = h >> 5, rem = h & 31;
      int lgi = (rem & 15) >> 2, j = ((rem >> 4) << 2) | (rem & 3);
      W2fl[(((q*4 + ni)*16) + liw)*W2FSTR + lgi*8 + j] = (unsigned short)b;
    }
    atomicAdd(&b2s[f], psum);   // rowsum of bf16 W2' for the -1 shift correction
  }
  if (tid < HID) b1l[tid] = b1g[tid] * LOG2E;
  __syncthreads();
  if (tid < OUTD) b2l[tid] = b2g[tid] - b2s[tid];        // b2' = b2 - ln2*rowsum(W2)
  __syncthreads();

  float b2v[4];
  #pragma unroll
  for (int ni = 0; ni < 4; ++ni) b2v[ni] = b2l[ni*16 + li];

  const long gw = (long)blockIdx.x*8 + w;

  auto loadIdx = [&](long t, int& a, int& b) {
    long e = t*WTILE + li;
    if (idx64) { int4v v = *(const int4v*)(edges_i + e*4); a = v[0]; b = v[2]; }
    else       { int2v v = *(const int2v*)(edges_i + e*2); a = v[0]; b = v[1]; }
  };
  // direct-to-fragment gather: lane(lg,li) pulls edge li's k-slice {8lg+32s+0..7}
  auto gload = [&](long t, int e0, int e1, f32x4* r) {
    const float* p0 = node_state + (long)e0*NFEAT + 8*lg;
    const float* p1 = node_state + (long)e1*NFEAT + 8*lg;
    const float* pe = edge_state + (t*WTILE + li)*NFEAT + 8*lg;
    r[0] = *(const f32x4*)(p0);      r[1] = *(const f32x4*)(p0 + 4);
    r[2] = *(const f32x4*)(p0 + 32); r[3] = *(const f32x4*)(p0 + 36);
    r[4] = *(const f32x4*)(p1);      r[5] = *(const f32x4*)(p1 + 4);
    r[6] = *(const f32x4*)(p1 + 32); r[7] = *(const f32x4*)(p1 + 36);
    r[8] = *(const f32x4*)(pe);      r[9] = *(const f32x4*)(pe + 4);
    r[10]= *(const f32x4*)(pe + 32); r[11]= *(const f32x4*)(pe + 36);
  };
  auto cvt8 = [&](f32x4 a, f32x4 b) {
    short8 s = { f2bf(a[0]), f2bf(a[1]), f2bf(a[2]), f2bf(a[3]),
                 f2bf(b[0]), f2bf(b[1]), f2bf(b[2]), f2bf(b[3]) };
    return s;
  };

  // ---- prologue ----
  int e0c, e1c, e0n = 0, e1n = 0;
  f32x4 rg[12];
  if (gw < tiles16) {
    loadIdx(gw, e0c, e1c);
    gload(gw, e0c, e1c, rg);
    if (gw + NWAVES < tiles16) loadIdx(gw + NWAVES, e0n, e1n);
  }

  // ---- barrier-free main loop ----
  #pragma unroll 1
  for (long t = gw; t < tiles16; t += NWAVES) {
    const bool hn = (t + NWAVES) < tiles16;

    // current tile f32 -> bf16 B-fragments (frees rg for the next prefetch)
    short8 bxr[6];
    #pragma unroll
    for (int p = 0; p < 3; ++p) {
      bxr[2*p]   = cvt8(rg[p*4 + 0], rg[p*4 + 1]);
      bxr[2*p+1] = cvt8(rg[p*4 + 2], rg[p*4 + 3]);
    }
    // issue next tile's gathers + indices two ahead (latency hidden by compute)
    int e0p = 0, e1p = 0;
    if (hn) gload(t + NWAVES, e0n, e1n, rg);
    if (t + 2*NWAVES < tiles16) loadIdx(t + 2*NWAVES, e0p, e1p);

    // GEMM1 (swapped, hid in two halves): z' = W1'.X^T + b1'
    short8 a2[4];
    #pragma unroll
    for (int half = 0; half < 2; ++half) {
      f32x4 acc[4];
      #pragma unroll
      for (int hi2 = 0; hi2 < 4; ++hi2)
        acc[hi2] = *(const f32x4*)(b1l + (half*4 + hi2)*16 + 4*lg);
      #pragma unroll
      for (int ks = 0; ks < 6; ++ks) {
        #pragma unroll
        for (int hi2 = 0; hi2 < 4; ++hi2) {
          short8 aw = *(const short8*)(W1l + ((half*4 + hi2)*16 + li)*W1STR + 32*ks + 8*lg);
          acc[hi2] = __builtin_amdgcn_mfma_f32_16x16x32_bf16(aw, bxr[ks], acc[hi2], 0, 0, 0);
        }
      }
      // H'' = log2(1+2^z'), packed straight into GEMM2 A fragments
      #pragma unroll
      for (int q2 = 0; q2 < 2; ++q2) {
        f32x4 lo = acc[2*q2], hi4 = acc[2*q2 + 1];
        short8 v = { f2bf(h2(lo[0])),  f2bf(h2(lo[1])),  f2bf(h2(lo[2])),  f2bf(h2(lo[3])),
                     f2bf(h2(hi4[0])), f2bf(h2(hi4[1])), f2bf(h2(hi4[2])), f2bf(h2(hi4[3])) };
        a2[half*2 + q2] = v;
      }
    }

    // GEMM2: out = H''.W2'^T + b2'
    f32x4 acc2[4];
    #pragma unroll
    for (int ni = 0; ni < 4; ++ni) { f32x4 z = {b2v[ni], b2v[ni], b2v[ni], b2v[ni]}; acc2[ni] = z; }
    #pragma unroll
    for (int q = 0; q < 4; ++q)
      #pragma unroll
      for (int ni = 0; ni < 4; ++ni) {
        short8 w2 = *(const short8*)(W2fl + ((q*4 + ni)*16 + li)*W2FSTR + lg*8);
        acc2[ni] = __builtin_amdgcn_mfma_f32_16x16x32_bf16(a2[q], w2, acc2[ni], 0, 0, 0);
      }

    // store: rows t*16+4lg+r, cols 16ni+li (64B contiguous per lane-group)
    { float* op = out + (t*WTILE + 4*lg)*OUTD + li;
      #pragma unroll
      for (int ni = 0; ni < 4; ++ni)
        #pragma unroll
        for (int r = 0; r < 4; ++r)
          op[(long)r*OUTD + ni*16] = acc2[ni][r];
    }

    e0n = e0p; e1n = e1p;
  }
}

extern "C" void kernel_launch(void* const* d_in, const int* in_sizes, int n_in,
                              void* d_out, int out_size, void* d_ws, size_t ws_size,
                              hipStream_t stream) {
  const float* edge_state = (const float*)d_in[0];
  const int*   edges_i    = (const int*)d_in[1];
  const float* node_state = (const float*)d_in[2];
  const float* W1g        = (const float*)d_in[3];
  const float* b1g        = (const float*)d_in[4];
  const float* W2g        = (const float*)d_in[5];
  const float* b2g        = (const float*)d_in[6];
  float* out = (float*)d_out;
  int*   flag = (int*)d_ws;

  const int E = in_sizes[0] / NFEAT;      // 1,000,000
  const int tiles16 = E / WTILE;          // 62,500

  detect_mode<<<dim3(1), dim3(256), 0, stream>>>(edges_i, flag);

  (void)hipFuncSetAttribute((const void*)edge_mlp,
                            hipFuncAttributeMaxDynamicSharedMemorySize, SMEM_BYTES);
  edge_mlp<<<dim3(GRID), dim3(TPB), SMEM_BYTES, stream>>>(
      edge_state, edges_i, node_state, W1g, b1g, W2g, b2g, out, flag, tiles16);
}